// Round 3
// baseline (1913.119 us; speedup 1.0000x reference)
//
#include <hip/hip_runtime.h>
#include <hip/hip_bf16.h>
#include <stdint.h>

typedef _Float16 f16;
typedef _Float16 f16x2 __attribute__((ext_vector_type(2)));
typedef _Float16 f16x4 __attribute__((ext_vector_type(4)));
typedef _Float16 f16x8 __attribute__((ext_vector_type(8)));
typedef float f32x4 __attribute__((ext_vector_type(4)));

#define T_STEPS 512
#define BATCH   128
#define DD      512

// workspace layout (bytes)
#define XP_OFF  0                         // f16 Xproj [512][128][512] = 67,108,864 B
#define WF_OFF  (67108864)                // f16 W_in  [512][512]      =    524,288 B
#define WHF_OFF (67108864 + 524288)       // f16 Whf frag-packed       =    524,288 B

__device__ __forceinline__ f16x2 pk(float a, float b) {
    return __builtin_bit_cast(f16x2, __builtin_amdgcn_cvt_pkrtz(a, b));
}

// ---------------------------------------------------------------- prep weights
// Wf: f16 copy of W_in for the gemm.
// Whf: W_h packed in A-fragment order for the rnn kernel:
//   idx = ((((w*4+mt)*16+ks)*64)+l)*8+j  ->  W_h[out][k],
//   out = w*64+mt*16+(l&15), k = ks*32+(l>>4)*8+j
__global__ __launch_bounds__(256) void prep_kernel(
        const float* __restrict__ Win, const float* __restrict__ Wh,
        f16* __restrict__ Wf, f16* __restrict__ Whf) {
    int idx = blockIdx.x * 256 + threadIdx.x;
    if (idx < 262144) {
        Wf[idx] = (f16)Win[idx];
        int j  = idx & 7;
        int l  = (idx >> 3) & 63;
        int ks = (idx >> 9) & 15;
        int mt = (idx >> 13) & 3;
        int w  = idx >> 15;
        int out = w * 64 + mt * 16 + (l & 15);
        int k   = ks * 32 + (l >> 4) * 8 + j;
        Whf[idx] = (f16)Wh[out * 512 + k];
    }
}

// ------------------------------------------------- Xproj = X @ Win^T + b_h (f16 out)
// direct-from-global MFMA, block=256 (2x2 waves), tile 128x128, grid (4, 512)
__global__ __launch_bounds__(256) void gemm_kernel(
        const float* __restrict__ X, const f16* __restrict__ Wf,
        const float* __restrict__ bias, f16* __restrict__ Xp) {
    const int lane = threadIdx.x & 63, wave = threadIdx.x >> 6;
    const int wm = wave >> 1, wn = wave & 1;
    const int q = lane >> 4, rl = lane & 15;
    const int m0 = blockIdx.y * 128 + wm * 64;
    const int n0 = blockIdx.x * 128 + wn * 64;

    f32x4 acc[4][4] = {};
    for (int k0 = 0; k0 < 512; k0 += 32) {
        const int k = k0 + q * 8;
        f16x8 af[4], bf[4];
#pragma unroll
        for (int i = 0; i < 4; i++) {
            const float* ap = X + (size_t)(m0 + i * 16 + rl) * 512 + k;
            float4 a0 = *(const float4*)ap;
            float4 a1 = *(const float4*)(ap + 4);
            f16x2 p0 = pk(a0.x, a0.y);
            f16x2 p1 = pk(a0.z, a0.w);
            f16x2 p2 = pk(a1.x, a1.y);
            f16x2 p3 = pk(a1.z, a1.w);
            f16x8 t;
            t[0] = p0[0]; t[1] = p0[1]; t[2] = p1[0]; t[3] = p1[1];
            t[4] = p2[0]; t[5] = p2[1]; t[6] = p3[0]; t[7] = p3[1];
            af[i] = t;
            bf[i] = *(const f16x8*)(Wf + (size_t)(n0 + i * 16 + rl) * 512 + k);
        }
#pragma unroll
        for (int i = 0; i < 4; i++)
#pragma unroll
            for (int j = 0; j < 4; j++)
                acc[i][j] = __builtin_amdgcn_mfma_f32_16x16x32_f16(af[i], bf[j], acc[i][j], 0, 0, 0);
    }
#pragma unroll
    for (int j = 0; j < 4; j++) {
        const int n = n0 + j * 16 + rl;
        const float bn = bias[n];
#pragma unroll
        for (int i = 0; i < 4; i++) {
#pragma unroll
            for (int r = 0; r < 4; r++) {
                const int m = m0 + i * 16 + q * 4 + r;
                Xp[(size_t)m * 512 + n] = (f16)(acc[i][j][r] + bn);
            }
        }
    }
}

// ----------------------------------------------------------------- recurrence
// Transposed MFMA form: C[out][batch] = W_h @ h^T, computed per step.
// 8 WGs x 16 batches; 512 threads = 8 waves, wave w owns output rows [64w,64w+64).
// W_h A-fragments register-resident (256 VGPRs/lane). h^T in LDS [16][520] f16
// (+8 f16 row pad -> conflict-free frag reads). Double-buffered, 1 barrier/step.
__global__ __launch_bounds__(512, 2) void rnn_kernel(
        const f16* __restrict__ Whf, const f16* __restrict__ Xp,
        float* __restrict__ out) {
    const int wg = blockIdx.x;          // 0..7
    const int tid = threadIdx.x;
    const int l = tid & 63, w = tid >> 6;
    const int bl = l & 15;              // batch lane (N-dim / C col)
    const int q = l >> 4;               // quad
    const int b = wg * 16 + bl;         // global batch

    __shared__ __align__(16) f16 hbuf[2][16][520];   // [buf][batch][512+8 pad]

    // load W_h A-fragments: af[mt][ks] = 8 f16, frag-packed in Whf
    f16x8 af[4][16];
    {
        const f16x8* wp = (const f16x8*)Whf + ((size_t)w * 4 * 16) * 64 + l;
#pragma unroll
        for (int mt = 0; mt < 4; mt++)
#pragma unroll
            for (int ks = 0; ks < 16; ks++)
                af[mt][ks] = wp[(mt * 16 + ks) * 64];
    }

    // zero h_0 (buffer 0)
    for (int i = tid; i < 16 * 520 / 2; i += 512) ((uint32_t*)hbuf[0])[i] = 0u;
    __syncthreads();

    // xp addresses: Xp[t][b][out], lane reads 4 consecutive outs per M-tile
    const f16* xpb = Xp + (size_t)b * 512 + w * 64 + q * 4;
    f16x4 xn[4];
#pragma unroll
    for (int mt = 0; mt < 4; mt++) xn[mt] = *(const f16x4*)(xpb + mt * 16);

    f32x4 acc[4];
    for (int t = 0; t < T_STEPS; t++) {
        f16x4 xc[4];
#pragma unroll
        for (int mt = 0; mt < 4; mt++) xc[mt] = xn[mt];
        // prefetch next step's xp (clamped at the end; value unused for t=511)
        const size_t tn = (size_t)(t < T_STEPS - 1 ? t + 1 : t) * (BATCH * 512);
#pragma unroll
        for (int mt = 0; mt < 4; mt++) xn[mt] = *(const f16x4*)(xpb + tn + mt * 16);

        const int rb = t & 1;
#pragma unroll
        for (int mt = 0; mt < 4; mt++) {
            acc[mt][0] = (float)xc[mt][0];
            acc[mt][1] = (float)xc[mt][1];
            acc[mt][2] = (float)xc[mt][2];
            acc[mt][3] = (float)xc[mt][3];
        }
        const f16* hrow = &hbuf[rb][bl][q * 8];
#pragma unroll
        for (int ks = 0; ks < 16; ks++) {
            f16x8 bf = *(const f16x8*)(hrow + ks * 32);
#pragma unroll
            for (int mt = 0; mt < 4; mt++)
                acc[mt] = __builtin_amdgcn_mfma_f32_16x16x32_f16(af[mt][ks], bf, acc[mt], 0, 0, 0);
        }
        // epilogue: sigmoid, pack, write h_{t+1}^T into the other buffer
        f16* wrow = &hbuf[1 - rb][bl][w * 64 + q * 4];
#pragma unroll
        for (int mt = 0; mt < 4; mt++) {
            float s0 = 1.0f / (1.0f + __expf(-acc[mt][0]));
            float s1 = 1.0f / (1.0f + __expf(-acc[mt][1]));
            float s2 = 1.0f / (1.0f + __expf(-acc[mt][2]));
            float s3 = 1.0f / (1.0f + __expf(-acc[mt][3]));
            f16x4 hv;
            f16x2 p01 = pk(s0, s1), p23 = pk(s2, s3);
            hv[0] = p01[0]; hv[1] = p01[1]; hv[2] = p23[0]; hv[3] = p23[1];
            *(f16x4*)(wrow + mt * 16) = hv;
            if (t == T_STEPS - 1) {
                float4 o = make_float4(s0, s1, s2, s3);
                *(float4*)(out + (size_t)b * 512 + w * 64 + mt * 16 + q * 4) = o;
            }
        }
        __syncthreads();
    }
}

extern "C" void kernel_launch(void* const* d_in, const int* in_sizes, int n_in,
                              void* d_out, int out_size, void* d_ws, size_t ws_size,
                              hipStream_t stream) {
    const float* X   = (const float*)d_in[0];
    const float* Win = (const float*)d_in[1];
    const float* Wh  = (const float*)d_in[2];
    const float* bh  = (const float*)d_in[3];
    float* out = (float*)d_out;
    char* ws = (char*)d_ws;
    f16* Xp  = (f16*)(ws + XP_OFF);
    f16* Wf  = (f16*)(ws + WF_OFF);
    f16* Whf = (f16*)(ws + WHF_OFF);

    prep_kernel<<<1024, 256, 0, stream>>>(Win, Wh, Wf, Whf);
    gemm_kernel<<<dim3(4, 512), 256, 0, stream>>>(X, Wf, bh, Xp);
    rnn_kernel<<<8, 512, 0, stream>>>(Whf, Xp, out);
}

// Round 5
// 1179.110 us; speedup vs baseline: 1.6225x; 1.6225x over previous
//
#include <hip/hip_runtime.h>
#include <hip/hip_bf16.h>
#include <stdint.h>

typedef _Float16 f16;
typedef _Float16 f16x2 __attribute__((ext_vector_type(2)));
typedef _Float16 f16x4 __attribute__((ext_vector_type(4)));
typedef _Float16 f16x8 __attribute__((ext_vector_type(8)));
typedef float f32x4 __attribute__((ext_vector_type(4)));
typedef int   i32x4 __attribute__((ext_vector_type(4)));

#define T_STEPS 512
#define BATCH   128
#define DD      512

// workspace layout (bytes)
#define XP_OFF  0                          // f16 Xproj [512][128][512] = 67,108,864
#define WF_OFF  (67108864)                 // f16 W_in  [512][512]      =    524,288
#define WHQ_OFF (67108864 + 524288)        // i8  W_h frag-packed       =    262,144
#define SC_OFF  (67108864 + 524288 + 262144) // f32 row scales [512]    =      2,048

__device__ __forceinline__ f16x2 pk(float a, float b) {
    return __builtin_bit_cast(f16x2, __builtin_amdgcn_cvt_pkrtz(a, b));
}

// ---------------------------------------------------------------- prep: Wf (f16 W_in)
__global__ __launch_bounds__(256) void prep_kernel(
        const float* __restrict__ Win, f16* __restrict__ Wf) {
    int idx = blockIdx.x * 256 + threadIdx.x;
    if (idx < 262144) Wf[idx] = (f16)Win[idx];
}

// ------------------------------------------- quantize W_h to i8, frag-packed, per-row scale
// one wave per output row o. A-frag packing: byte index
//   (((w*4+mt)*8+ks)*64 + l)*16 + j  ->  W_h[out][k]
//   out = w*64+mt*16+(l&15), k = ks*64+(l>>4)*16+j
// scales[o] = m/(127*127): dequant of (W/s_w)*(h*127) needs s_w/127.
__global__ __launch_bounds__(64) void quant_kernel(
        const float* __restrict__ Wh, char* __restrict__ Whq, float* __restrict__ scales) {
    const int o = blockIdx.x, t = threadIdx.x;
    const float* row = Wh + (size_t)o * 512;
    float v[8];
    float m = 0.f;
#pragma unroll
    for (int j = 0; j < 8; j++) { v[j] = row[t * 8 + j]; m = fmaxf(m, fabsf(v[j])); }
#pragma unroll
    for (int off = 32; off > 0; off >>= 1) m = fmaxf(m, __shfl_xor(m, off));
    if (t == 0) scales[o] = m * (1.0f / (127.0f * 127.0f));
    const float inv = 127.0f / m;
    const int w = o >> 6, mt = (o >> 4) & 3, rl = o & 15;
    const int k0 = t * 8;
    const int ks = k0 >> 6, q = (k0 >> 4) & 3, j0 = k0 & 15;
    const int l = q * 16 + rl;
    char* dst = Whq + ((size_t)(((w * 4 + mt) * 8 + ks) * 64 + l)) * 16 + j0;
#pragma unroll
    for (int j = 0; j < 8; j++) dst[j] = (char)rintf(v[j] * inv);
}

// ------------------------------------------------- Xproj = X @ Win^T + b_h (f16 out)
// direct-from-global MFMA, register double-buffered prefetch of next k0 tile
__global__ __launch_bounds__(256, 2) void gemm_kernel(
        const float* __restrict__ X, const f16* __restrict__ Wf,
        const float* __restrict__ bias, f16* __restrict__ Xp) {
    const int lane = threadIdx.x & 63, wave = threadIdx.x >> 6;
    const int wm = wave >> 1, wn = wave & 1;
    const int q = lane >> 4, rl = lane & 15;
    const int m0 = blockIdx.y * 128 + wm * 64;
    const int n0 = blockIdx.x * 128 + wn * 64;

    const float* aBase[4];
    const f16*   bBase[4];
#pragma unroll
    for (int i = 0; i < 4; i++) {
        aBase[i] = X  + (size_t)(m0 + i * 16 + rl) * 512 + q * 8;
        bBase[i] = Wf + (size_t)(n0 + i * 16 + rl) * 512 + q * 8;
    }

    float4 aR[4][2]; f16x8 bR[4];
#pragma unroll
    for (int i = 0; i < 4; i++) {
        aR[i][0] = *(const float4*)(aBase[i]);
        aR[i][1] = *(const float4*)(aBase[i] + 4);
        bR[i]    = *(const f16x8*)(bBase[i]);
    }

    f32x4 acc[4][4] = {};
    for (int k0 = 0; k0 < 512; k0 += 32) {
        const int kn = (k0 + 32 < 512) ? k0 + 32 : k0;
        float4 aN[4][2]; f16x8 bN[4];
#pragma unroll
        for (int i = 0; i < 4; i++) {           // prefetch next tile
            aN[i][0] = *(const float4*)(aBase[i] + kn);
            aN[i][1] = *(const float4*)(aBase[i] + kn + 4);
            bN[i]    = *(const f16x8*)(bBase[i] + kn);
        }
        f16x8 af[4];
#pragma unroll
        for (int i = 0; i < 4; i++) {           // convert current A tile
            f16x2 p0 = pk(aR[i][0].x, aR[i][0].y);
            f16x2 p1 = pk(aR[i][0].z, aR[i][0].w);
            f16x2 p2 = pk(aR[i][1].x, aR[i][1].y);
            f16x2 p3 = pk(aR[i][1].z, aR[i][1].w);
            f16x8 tv;
            tv[0] = p0[0]; tv[1] = p0[1]; tv[2] = p1[0]; tv[3] = p1[1];
            tv[4] = p2[0]; tv[5] = p2[1]; tv[6] = p3[0]; tv[7] = p3[1];
            af[i] = tv;
        }
#pragma unroll
        for (int i = 0; i < 4; i++)
#pragma unroll
            for (int j = 0; j < 4; j++)
                acc[i][j] = __builtin_amdgcn_mfma_f32_16x16x32_f16(af[i], bR[j], acc[i][j], 0, 0, 0);
#pragma unroll
        for (int i = 0; i < 4; i++) { aR[i][0] = aN[i][0]; aR[i][1] = aN[i][1]; bR[i] = bN[i]; }
    }
#pragma unroll
    for (int j = 0; j < 4; j++) {
        const int n = n0 + j * 16 + rl;
        const float bn = bias[n];
#pragma unroll
        for (int i = 0; i < 4; i++)
#pragma unroll
            for (int r = 0; r < 4; r++) {
                const int m = m0 + i * 16 + q * 4 + r;
                Xp[(size_t)m * 512 + n] = (f16)(acc[i][j][r] + bn);
            }
    }
}

// ----------------------------------------------------------------- recurrence (i8 MFMA)
// C[out][batch] = Wq @ hq^T per step. 8 WGs x 16 batches; 8 waves, wave w owns
// rows [64w,64w+64). i8 A-frags register-resident (128 VGPRs). h^T i8 in LDS
// [16][528] (+16B pad). Double-buffered, 1 barrier/step.
__global__ __launch_bounds__(512, 2) void rnn_kernel(
        const char* __restrict__ Whq, const float* __restrict__ scales,
        const f16* __restrict__ Xp, float* __restrict__ out) {
    const int wg = blockIdx.x;          // 0..7
    const int tid = threadIdx.x;
    const int l = tid & 63, w = tid >> 6;
    const int bl = l & 15;              // batch lane (N / C col)
    const int q = l >> 4;               // k-quad / C row quad
    const int b = wg * 16 + bl;

    __shared__ __align__(16) char hT[2][16][528];   // [buf][batch][512+16 pad] i8

    // register-resident i8 A-fragments: af[mt][ks], 4 dwords each = 128 VGPRs
    i32x4 af[4][8];
    {
        const i32x4* wp = (const i32x4*)Whq;
#pragma unroll
        for (int mt = 0; mt < 4; mt++)
#pragma unroll
            for (int ks = 0; ks < 8; ks++)
                af[mt][ks] = wp[((w * 4 + mt) * 8 + ks) * 64 + l];
    }
    // per-lane output-row scales (already /127^2)
    float sc[4][4];
#pragma unroll
    for (int mt = 0; mt < 4; mt++)
#pragma unroll
        for (int r = 0; r < 4; r++)
            sc[mt][r] = scales[w * 64 + mt * 16 + q * 4 + r];

    for (int i = tid; i < 16 * 528 / 4; i += 512) ((uint32_t*)hT[0])[i] = 0u;
    __syncthreads();

    const f16* xpb = Xp + (size_t)b * 512 + w * 64 + q * 4;
    f16x4 xn[4];
#pragma unroll
    for (int mt = 0; mt < 4; mt++) xn[mt] = *(const f16x4*)(xpb + mt * 16);

    for (int t = 0; t < T_STEPS; t++) {
        f16x4 xc[4];
#pragma unroll
        for (int mt = 0; mt < 4; mt++) xc[mt] = xn[mt];
        const size_t tn = (size_t)(t < T_STEPS - 1 ? t + 1 : t) * (BATCH * 512);
#pragma unroll
        for (int mt = 0; mt < 4; mt++) xn[mt] = *(const f16x4*)(xpb + tn + mt * 16);

        const int rb = t & 1;
        i32x4 acc[4] = {};
        const char* hrow = &hT[rb][bl][q * 16];
#pragma unroll
        for (int ks = 0; ks < 8; ks++) {
            i32x4 bfr = *(const i32x4*)(hrow + ks * 64);
#pragma unroll
            for (int mt = 0; mt < 4; mt++)
                acc[mt] = __builtin_amdgcn_mfma_i32_16x16x64_i8(af[mt][ks], bfr, acc[mt], 0, 0, 0);
        }
        // epilogue: scale, +xp, sigmoid, quantize to i8, write next h^T
#pragma unroll
        for (int mt = 0; mt < 4; mt++) {
            float s0, s1, s2, s3;
            {
                float v0 = (float)acc[mt][0] * sc[mt][0] + (float)xc[mt][0];
                float v1 = (float)acc[mt][1] * sc[mt][1] + (float)xc[mt][1];
                float v2 = (float)acc[mt][2] * sc[mt][2] + (float)xc[mt][2];
                float v3 = (float)acc[mt][3] * sc[mt][3] + (float)xc[mt][3];
                s0 = 1.0f / (1.0f + __expf(-v0));
                s1 = 1.0f / (1.0f + __expf(-v1));
                s2 = 1.0f / (1.0f + __expf(-v2));
                s3 = 1.0f / (1.0f + __expf(-v3));
            }
            uint32_t pkq = (uint32_t)(int)(s0 * 127.f + 0.5f)
                         | ((uint32_t)(int)(s1 * 127.f + 0.5f) << 8)
                         | ((uint32_t)(int)(s2 * 127.f + 0.5f) << 16)
                         | ((uint32_t)(int)(s3 * 127.f + 0.5f) << 24);
            *(uint32_t*)&hT[1 - rb][bl][w * 64 + mt * 16 + q * 4] = pkq;
            if (t == T_STEPS - 1) {
                *(float4*)(out + (size_t)b * 512 + w * 64 + mt * 16 + q * 4) =
                    make_float4(s0, s1, s2, s3);
            }
        }
        __syncthreads();
    }
}

extern "C" void kernel_launch(void* const* d_in, const int* in_sizes, int n_in,
                              void* d_out, int out_size, void* d_ws, size_t ws_size,
                              hipStream_t stream) {
    const float* X   = (const float*)d_in[0];
    const float* Win = (const float*)d_in[1];
    const float* Wh  = (const float*)d_in[2];
    const float* bh  = (const float*)d_in[3];
    float* out = (float*)d_out;
    char* ws = (char*)d_ws;
    f16* Xp      = (f16*)(ws + XP_OFF);
    f16* Wf      = (f16*)(ws + WF_OFF);
    char* Whq    = (char*)(ws + WHQ_OFF);
    float* Sc    = (float*)(ws + SC_OFF);

    prep_kernel<<<1024, 256, 0, stream>>>(Win, Wf);
    quant_kernel<<<512, 64, 0, stream>>>(Wh, Whq, Sc);
    gemm_kernel<<<dim3(4, 512), 256, 0, stream>>>(X, Wf, bh, Xp);
    rnn_kernel<<<8, 512, 0, stream>>>(Whq, Sc, Xp, out);
}